// Round 3
// baseline (171.635 us; speedup 1.0000x reference)
//
#include <hip/hip_runtime.h>
#include <hip/hip_bf16.h>

#define N_X    65536
#define N_IND  1024
#define N_DESC 64
#define NCHUNK 4
#define CHUNK  (N_IND / NCHUNK)   // 256 inducing points per i-chunk
#define TILES  (CHUNK / 16)       // 16 MFMA row-tiles per chunk
#define L2E    1.4426950408889634f
#define L2E2   2.8853900817779268f

typedef __attribute__((ext_vector_type(8))) short  short8;
typedef __attribute__((ext_vector_type(4))) float  f32x4;

static __device__ __forceinline__ ushort f2bf(float f) {
    union { float f; unsigned u; } a; a.f = f;
    unsigned r = a.u + 0x7FFF + ((a.u >> 16) & 1);   // RNE to bf16
    return (ushort)(r >> 16);
}
static __device__ __forceinline__ float bf2f(ushort h) {
    union { unsigned u; float f; } a; a.u = (unsigned)h << 16;
    return a.f;
}

// ---------------------------------------------------------------------------
// prep (shared shape): row r of src (64 f32) -> bf16 row * exp(-ls/2) in dst,
// plus sq2[r] = log2e * sum(bf16-rounded weighted row ^2).
// 4 lanes per row (q = 16-k quarter): fully coalesced 64B/lane reads,
// 32B/lane writes.
// ---------------------------------------------------------------------------
template <int NROWS>
__global__ __launch_bounds__(256) void igpr_prep(
        const float* __restrict__ src, const float* __restrict__ ls,
        ushort* __restrict__ dst, float* __restrict__ sq2) {
    int tid = blockIdx.x * 256 + threadIdx.x;
    int r = tid >> 2, q = tid & 3;
    if (r >= NROWS) return;
    float sq = 0.f;
    ushort hb[16];
#pragma unroll
    for (int m = 0; m < 4; ++m) {
        float4 v = *reinterpret_cast<const float4*>(&src[r * N_DESC + q * 16 + m * 4]);
        float vv[4] = {v.x, v.y, v.z, v.w};
#pragma unroll
        for (int e = 0; e < 4; ++e) {
            float w = __expf(-0.5f * ls[q * 16 + m * 4 + e]);
            ushort h = f2bf(vv[e] * w);
            hb[m * 4 + e] = h;
            float vr = bf2f(h);
            sq = fmaf(vr, vr, sq);
        }
    }
    unsigned u[8];
#pragma unroll
    for (int t = 0; t < 8; ++t)
        u[t] = (unsigned)hb[2 * t] | ((unsigned)hb[2 * t + 1] << 16);
    uint4* d4 = reinterpret_cast<uint4*>(&dst[r * N_DESC + q * 16]);
    d4[0] = make_uint4(u[0], u[1], u[2], u[3]);
    d4[1] = make_uint4(u[4], u[5], u[6], u[7]);
    sq += __shfl_xor(sq, 1);
    sq += __shfl_xor(sq, 2);
    if (q == 0) sq2[r] = sq * L2E;
}

// ---------------------------------------------------------------------------
// main: wave owns 64 x-columns (4 strips of 16). B-frags = 8 dense 16B loads
// from precomputed xwb. A-frags register-double-buffered one tile ahead.
// acc = mfma(zwA, xwB); arg = 2*log2e*acc - (zs2[i] + xs2[j]);
// accJ += alpha[i]*exp2(arg).  C/D: col = lane&15, row = 4*(lane>>4)+reg.
// __launch_bounds__(256,4): cap VGPR at 128 -> 4 waves/SIMD, whole grid
// (1024 blocks = 16 waves/CU) resident in one generation.
// ---------------------------------------------------------------------------
__global__ __launch_bounds__(256, 4) void igpr_main(
        const ushort* __restrict__ xwb, const float* __restrict__ xs2,
        const ushort* __restrict__ zwb, const float* __restrict__ zs2,
        const float* __restrict__ alpha, float* __restrict__ part) {
    const int lane = threadIdx.x & 63;
    const int wave = threadIdx.x >> 6;
    const int p = lane & 15;          // point index within strip
    const int g = lane >> 4;          // k-group
    const int j0 = blockIdx.x * 256 + wave * 64;
    const int c  = blockIdx.y;        // i-chunk

    short8 b[4][2];
    float xs2v[4];
#pragma unroll
    for (int s = 0; s < 4; ++s) {
        const ushort* xr = xwb + (size_t)(j0 + s * 16 + p) * N_DESC;
        b[s][0] = *reinterpret_cast<const short8*>(xr + g * 8);
        b[s][1] = *reinterpret_cast<const short8*>(xr + 32 + g * 8);
        xs2v[s] = xs2[j0 + s * 16 + p];
    }

    float accJ[4] = {0.f, 0.f, 0.f, 0.f};
    const int ibase = c * CHUNK;

    // prefetch tile 0 A-frags
    const ushort* zr0 = zwb + (size_t)(ibase + p) * N_DESC;
    short8 a0 = *reinterpret_cast<const short8*>(zr0 + g * 8);
    short8 a1 = *reinterpret_cast<const short8*>(zr0 + 32 + g * 8);

    for (int it = 0; it < TILES; ++it) {
        const int i0 = ibase + it * 16;
        float4 z2 = *reinterpret_cast<const float4*>(&zs2[i0 + g * 4]);
        float4 a4 = *reinterpret_cast<const float4*>(&alpha[i0 + g * 4]);

        short8 ca0 = a0, ca1 = a1;
        if (it + 1 < TILES) {
            const ushort* nzr = zwb + (size_t)(i0 + 16 + p) * N_DESC;
            a0 = *reinterpret_cast<const short8*>(nzr + g * 8);
            a1 = *reinterpret_cast<const short8*>(nzr + 32 + g * 8);
        }

        f32x4 acc[4];
#pragma unroll
        for (int s = 0; s < 4; ++s) {
            f32x4 t = {0.f, 0.f, 0.f, 0.f};
            t = __builtin_amdgcn_mfma_f32_16x16x32_bf16(ca0, b[s][0], t, 0, 0, 0);
            t = __builtin_amdgcn_mfma_f32_16x16x32_bf16(ca1, b[s][1], t, 0, 0, 0);
            acc[s] = t;
        }

        float z2v[4] = {z2.x, z2.y, z2.z, z2.w};
        float a4v[4] = {a4.x, a4.y, a4.z, a4.w};
#pragma unroll
        for (int s = 0; s < 4; ++s) {
#pragma unroll
            for (int e = 0; e < 4; ++e) {
                float arg = fmaf(acc[s][e], L2E2, -(z2v[e] + xs2v[s]));
                float pv  = __builtin_amdgcn_exp2f(arg);
                accJ[s]   = fmaf(a4v[e], pv, accJ[s]);
            }
        }
    }

#pragma unroll
    for (int s = 0; s < 4; ++s) {
        float r = accJ[s];
        r += __shfl_xor(r, 16);
        r += __shfl_xor(r, 32);
        if (g == 0) part[(size_t)c * N_X + j0 + s * 16 + p] = r;
    }
}

// ---------------------------------------------------------------------------
// reduce: out[j] = sum_c part[c][j]
// ---------------------------------------------------------------------------
__global__ void igpr_reduce(const float* __restrict__ part,
                            float* __restrict__ out) {
    int j = blockIdx.x * 256 + threadIdx.x;
    float s = 0.f;
#pragma unroll
    for (int c = 0; c < NCHUNK; ++c) s += part[(size_t)c * N_X + j];
    out[j] = s;
}

extern "C" void kernel_launch(void* const* d_in, const int* in_sizes, int n_in,
                              void* d_out, int out_size, void* d_ws, size_t ws_size,
                              hipStream_t stream) {
    const float* x     = (const float*)d_in[0];   // (65536, 64)
    const float* z     = (const float*)d_in[1];   // (1024, 64)
    const float* alpha = (const float*)d_in[2];   // (1024,)
    const float* ls    = (const float*)d_in[3];   // (64,)
    float* out = (float*)d_out;                   // (65536, 1)

    // ws layout:
    //   zwb  ushort[1024*64]        (128 KB)
    //   xwb  ushort[65536*64]       (8 MB)
    //   zs2  f32[1024]
    //   xs2  f32[65536]
    //   part f32[4*65536]
    ushort* zwb  = (ushort*)d_ws;
    ushort* xwb  = zwb + (size_t)N_IND * N_DESC;
    float*  zs2  = (float*)(xwb + (size_t)N_X * N_DESC);
    float*  xs2  = zs2 + N_IND;
    float*  part = xs2 + N_X;

    igpr_prep<N_IND><<<dim3(16), dim3(256), 0, stream>>>(z, ls, zwb, zs2);
    igpr_prep<N_X><<<dim3(N_X * 4 / 256), dim3(256), 0, stream>>>(x, ls, xwb, xs2);
    igpr_main<<<dim3(N_X / 256, NCHUNK), dim3(256), 0, stream>>>(xwb, xs2, zwb, zs2, alpha, part);
    igpr_reduce<<<dim3(N_X / 256), dim3(256), 0, stream>>>(part, out);
}